// Round 1
// baseline (3453.511 us; speedup 1.0000x reference)
//
#include <hip/hip_runtime.h>

#define Nn 100000
#define Ee 1600000
#define IND 256
#define HD 128
#define NCLS 40

// ---------------------------------------------------------------------------
// Aggregation: agg[dst] += adj_embed[src], deg[dst] += 1  (fp32 atomics)
// 32 threads per edge, each handles 4 contiguous columns (float4 gather).
// ---------------------------------------------------------------------------
extern "C" __global__ void __launch_bounds__(256)
linkx_agg(const int* __restrict__ ei, const float* __restrict__ emb,
          float* __restrict__ agg, float* __restrict__ deg) {
    int gid = blockIdx.x * 256 + threadIdx.x;
    int e = gid >> 5;
    if (e >= Ee) return;
    int g = gid & 31;
    int src = ei[e];
    int dst = ei[Ee + e];
    int c = g * 4;
    float4 v = *(const float4*)(emb + (size_t)src * HD + c);
    float* a = agg + (size_t)dst * HD + c;
    atomicAdd(a + 0, v.x);
    atomicAdd(a + 1, v.y);
    atomicAdd(a + 2, v.z);
    atomicAdd(a + 3, v.w);
    if (g == 0) atomicAdd(deg + dst, 1.0f);
}

// ---------------------------------------------------------------------------
// 4x4 register-blocked tile GEMM: acc[i][j] += sum_k src[r0+i][k] * W[k][c0+j]
// src is an LDS tile (stride S), W is global (row-major, 128 cols), K mult of 4
// ---------------------------------------------------------------------------
__device__ __forceinline__ void tile_mm(const float* src, int S,
                                        const float* __restrict__ W,
                                        int K, int r0, int c0, float acc[4][4]) {
    for (int k = 0; k < K; k += 4) {
        float4 a0 = *(const float4*)(src + (r0 + 0) * S + k);
        float4 a1 = *(const float4*)(src + (r0 + 1) * S + k);
        float4 a2 = *(const float4*)(src + (r0 + 2) * S + k);
        float4 a3 = *(const float4*)(src + (r0 + 3) * S + k);
        float4 w0 = *(const float4*)(W + (k + 0) * HD + c0);
        float4 w1 = *(const float4*)(W + (k + 1) * HD + c0);
        float4 w2 = *(const float4*)(W + (k + 2) * HD + c0);
        float4 w3 = *(const float4*)(W + (k + 3) * HD + c0);
#define ROW(i, av)                                                  \
        acc[i][0] += av.x * w0.x + av.y * w1.x + av.z * w2.x + av.w * w3.x; \
        acc[i][1] += av.x * w0.y + av.y * w1.y + av.z * w2.y + av.w * w3.y; \
        acc[i][2] += av.x * w0.z + av.y * w1.z + av.z * w2.z + av.w * w3.z; \
        acc[i][3] += av.x * w0.w + av.y * w1.w + av.z * w2.w + av.w * w3.w;
        ROW(0, a0) ROW(1, a1) ROW(2, a2) ROW(3, a3)
#undef ROW
    }
}

// ---------------------------------------------------------------------------
// Fused per-node-tile MLP: 32 nodes per block, 256 threads.
// LDS: bufx (32x256 = 32KB, later split into two 32x128 slots A|B), buft (16KB).
// Lifetimes: xs->bufx; t1->buft; hx->slotA; ha_raw->slotB; t2->buft;
//            ha->slotB; h->buft; h2->buft (in place); logits->global.
// ---------------------------------------------------------------------------
extern "C" __global__ void __launch_bounds__(256)
linkx_mlp(const float* __restrict__ x, const float* __restrict__ agg,
          const float* __restrict__ deg,
          const float* __restrict__ wx1, const float* __restrict__ bx1,
          const float* __restrict__ wx2, const float* __restrict__ bx2,
          const float* __restrict__ wa1, const float* __restrict__ ba1,
          const float* __restrict__ wa2, const float* __restrict__ ba2,
          const float* __restrict__ ww1, const float* __restrict__ bw1,
          const float* __restrict__ wcm, const float* __restrict__ bcv,
          float* __restrict__ out) {
    __shared__ float bufx[32 * 256];
    __shared__ float buft[32 * 128];
    const int t = threadIdx.x;
    const int node0 = blockIdx.x * 32;
    const int r0 = (t >> 5) * 4;   // 8 row-groups of 4 rows
    const int c0 = (t & 31) * 4;   // 32 col-groups of 4 cols
    float* sA = bufx;              // 32x128 slot A
    float* sB = bufx + 32 * HD;    // 32x128 slot B
    float acc[4][4];

    // step1: load x tile -> bufx [32][256]
    for (int idx = t; idx < 2048; idx += 256) {
        int r = idx >> 6;
        int c = (idx & 63) * 4;
        *(float4*)(bufx + r * IND + c) =
            *(const float4*)(x + (size_t)(node0 + r) * IND + c);
    }
    __syncthreads();

    // step2: t1 = relu(x @ wx1 + bx1) -> buft
#pragma unroll
    for (int i = 0; i < 4; i++)
#pragma unroll
        for (int j = 0; j < 4; j++) acc[i][j] = 0.f;
    tile_mm(bufx, IND, wx1, IND, r0, c0, acc);
    {
        float4 b = *(const float4*)(bx1 + c0);
#pragma unroll
        for (int i = 0; i < 4; i++) {
            float4 v;
            v.x = fmaxf(acc[i][0] + b.x, 0.f);
            v.y = fmaxf(acc[i][1] + b.y, 0.f);
            v.z = fmaxf(acc[i][2] + b.z, 0.f);
            v.w = fmaxf(acc[i][3] + b.w, 0.f);
            *(float4*)(buft + (r0 + i) * HD + c0) = v;
        }
    }
    __syncthreads();

    // step3: hx = t1 @ wx2 + bx2 (no relu) -> slot A
#pragma unroll
    for (int i = 0; i < 4; i++)
#pragma unroll
        for (int j = 0; j < 4; j++) acc[i][j] = 0.f;
    tile_mm(buft, HD, wx2, HD, r0, c0, acc);
    {
        float4 b = *(const float4*)(bx2 + c0);
#pragma unroll
        for (int i = 0; i < 4; i++) {
            float4 v;
            v.x = acc[i][0] + b.x;
            v.y = acc[i][1] + b.y;
            v.z = acc[i][2] + b.z;
            v.w = acc[i][3] + b.w;
            *(float4*)(sA + (r0 + i) * HD + c0) = v;
        }
    }
    __syncthreads();

    // step4: ha_raw = agg/max(deg,1) -> slot B
    for (int idx = t; idx < 1024; idx += 256) {
        int r = idx >> 5;
        int c = (idx & 31) * 4;
        float4 v = *(const float4*)(agg + (size_t)(node0 + r) * HD + c);
        float inv = 1.0f / fmaxf(deg[node0 + r], 1.0f);
        v.x *= inv; v.y *= inv; v.z *= inv; v.w *= inv;
        *(float4*)(sB + r * HD + c) = v;
    }
    __syncthreads();

    // step5: t2 = relu(ha_raw @ wa1 + ba1) -> buft
#pragma unroll
    for (int i = 0; i < 4; i++)
#pragma unroll
        for (int j = 0; j < 4; j++) acc[i][j] = 0.f;
    tile_mm(sB, HD, wa1, HD, r0, c0, acc);
    {
        float4 b = *(const float4*)(ba1 + c0);
#pragma unroll
        for (int i = 0; i < 4; i++) {
            float4 v;
            v.x = fmaxf(acc[i][0] + b.x, 0.f);
            v.y = fmaxf(acc[i][1] + b.y, 0.f);
            v.z = fmaxf(acc[i][2] + b.z, 0.f);
            v.w = fmaxf(acc[i][3] + b.w, 0.f);
            *(float4*)(buft + (r0 + i) * HD + c0) = v;
        }
    }
    __syncthreads();

    // step6: ha = t2 @ wa2 + ba2 (no relu) -> slot B
#pragma unroll
    for (int i = 0; i < 4; i++)
#pragma unroll
        for (int j = 0; j < 4; j++) acc[i][j] = 0.f;
    tile_mm(buft, HD, wa2, HD, r0, c0, acc);
    {
        float4 b = *(const float4*)(ba2 + c0);
#pragma unroll
        for (int i = 0; i < 4; i++) {
            float4 v;
            v.x = acc[i][0] + b.x;
            v.y = acc[i][1] + b.y;
            v.z = acc[i][2] + b.z;
            v.w = acc[i][3] + b.w;
            *(float4*)(sB + (r0 + i) * HD + c0) = v;
        }
    }
    __syncthreads();

    // step7: h = relu(hx @ ww1[0:128] + ha @ ww1[128:256] + bw1) -> buft
#pragma unroll
    for (int i = 0; i < 4; i++)
#pragma unroll
        for (int j = 0; j < 4; j++) acc[i][j] = 0.f;
    tile_mm(sA, HD, ww1, HD, r0, c0, acc);
    tile_mm(sB, HD, ww1 + HD * HD, HD, r0, c0, acc);
    {
        float4 b = *(const float4*)(bw1 + c0);
#pragma unroll
        for (int i = 0; i < 4; i++) {
            float4 v;
            v.x = fmaxf(acc[i][0] + b.x, 0.f);
            v.y = fmaxf(acc[i][1] + b.y, 0.f);
            v.z = fmaxf(acc[i][2] + b.z, 0.f);
            v.w = fmaxf(acc[i][3] + b.w, 0.f);
            *(float4*)(buft + (r0 + i) * HD + c0) = v;
        }
    }
    __syncthreads();

    // step8: h2 = relu(h + hx + ha) in-place in buft
#pragma unroll
    for (int i = 0; i < 4; i++) {
        float4 h = *(const float4*)(buft + (r0 + i) * HD + c0);
        float4 a = *(const float4*)(sA + (r0 + i) * HD + c0);
        float4 b = *(const float4*)(sB + (r0 + i) * HD + c0);
        h.x = fmaxf(h.x + a.x + b.x, 0.f);
        h.y = fmaxf(h.y + a.y + b.y, 0.f);
        h.z = fmaxf(h.z + a.z + b.z, 0.f);
        h.w = fmaxf(h.w + a.w + b.w, 0.f);
        *(float4*)(buft + (r0 + i) * HD + c0) = h;
    }
    __syncthreads();

    // step9: logits = h2 @ wc + bc -> global
    for (int idx = t; idx < 32 * NCLS; idx += 256) {
        int r = idx / NCLS;
        int c = idx - r * NCLS;
        float s = bcv[c];
        const float* hrow = buft + r * HD;
#pragma unroll 4
        for (int k = 0; k < HD; k++) s += hrow[k] * wcm[k * NCLS + c];
        out[(size_t)(node0 + r) * NCLS + c] = s;
    }
}

extern "C" void kernel_launch(void* const* d_in, const int* in_sizes, int n_in,
                              void* d_out, int out_size, void* d_ws, size_t ws_size,
                              hipStream_t stream) {
    const float* x   = (const float*)d_in[0];
    const int*   ei  = (const int*)d_in[1];
    const float* emb = (const float*)d_in[2];
    const float* wx1 = (const float*)d_in[3];
    const float* bx1 = (const float*)d_in[4];
    const float* wx2 = (const float*)d_in[5];
    const float* bx2 = (const float*)d_in[6];
    const float* wa1 = (const float*)d_in[7];
    const float* ba1 = (const float*)d_in[8];
    const float* wa2 = (const float*)d_in[9];
    const float* ba2 = (const float*)d_in[10];
    const float* ww1 = (const float*)d_in[11];
    const float* bw1 = (const float*)d_in[12];
    const float* wc  = (const float*)d_in[13];
    const float* bc  = (const float*)d_in[14];
    float* out = (float*)d_out;

    float* agg = (float*)d_ws;                 // [Nn * HD]
    float* deg = agg + (size_t)Nn * HD;        // [Nn]

    hipMemsetAsync(d_ws, 0, (size_t)(Nn * HD + Nn) * sizeof(float), stream);
    linkx_agg<<<(Ee * 32) / 256, 256, 0, stream>>>(ei, emb, agg, deg);
    linkx_mlp<<<Nn / 32, 256, 0, stream>>>(x, agg, deg,
                                           wx1, bx1, wx2, bx2,
                                           wa1, ba1, wa2, ba2,
                                           ww1, bw1, wc, bc, out);
}

// Round 2
// 1042.499 us; speedup vs baseline: 3.3127x; 3.3127x over previous
//
#include <hip/hip_runtime.h>

#define Nn 100000
#define Ee 1600000
#define IND 256
#define HD 128
#define NCLS 40
#define NBLK 391   // ceil(Nn/256)

// ---------------------------------------------------------------------------
// CSR build: histogram -> exclusive scan (3 kernels) -> bucket scatter.
// All int atomics on small cache-resident arrays (vs 205M fp32 HBM atomics).
// ---------------------------------------------------------------------------
extern "C" __global__ void __launch_bounds__(256)
k_hist(const int* __restrict__ ei, int* __restrict__ counts) {
    int e = blockIdx.x * 256 + threadIdx.x;
    if (e < Ee) atomicAdd(&counts[ei[Ee + e]], 1);
}

extern "C" __global__ void __launch_bounds__(256)
k_scan1(const int* __restrict__ counts, int* __restrict__ bsum) {
    __shared__ int s[256];
    int t = threadIdx.x;
    int i = blockIdx.x * 256 + t;
    s[t] = (i < Nn) ? counts[i] : 0;
    __syncthreads();
    for (int d = 128; d > 0; d >>= 1) {
        if (t < d) s[t] += s[t + d];
        __syncthreads();
    }
    if (t == 0) bsum[blockIdx.x] = s[0];
}

extern "C" __global__ void __launch_bounds__(512)
k_scan2(int* __restrict__ bsum) {
    __shared__ int s[512];
    int t = threadIdx.x;
    int v = (t < NBLK) ? bsum[t] : 0;
    s[t] = v;
    __syncthreads();
    for (int d = 1; d < 512; d <<= 1) {
        int x = (t >= d) ? s[t - d] : 0;
        __syncthreads();
        s[t] += x;
        __syncthreads();
    }
    if (t < NBLK) bsum[t] = s[t] - v;  // exclusive scan of block sums
}

extern "C" __global__ void __launch_bounds__(256)
k_scan3(const int* __restrict__ counts, const int* __restrict__ bsum,
        int* __restrict__ offsets) {
    __shared__ int s[256];
    int t = threadIdx.x;
    int i = blockIdx.x * 256 + t;
    int v = (i < Nn) ? counts[i] : 0;
    s[t] = v;
    __syncthreads();
    for (int d = 1; d < 256; d <<= 1) {
        int x = (t >= d) ? s[t - d] : 0;
        __syncthreads();
        s[t] += x;
        __syncthreads();
    }
    if (i < Nn) offsets[i] = bsum[blockIdx.x] + s[t] - v;
    if (i == 0) offsets[Nn] = Ee;
}

extern "C" __global__ void __launch_bounds__(256)
k_scatter(const int* __restrict__ ei, const int* __restrict__ offsets,
          int* __restrict__ pos, int* __restrict__ bucket) {
    int e = blockIdx.x * 256 + threadIdx.x;
    if (e >= Ee) return;
    int dst = ei[Ee + e];
    int p = offsets[dst] + atomicAdd(&pos[dst], 1);
    bucket[p] = ei[e];
}

// ---------------------------------------------------------------------------
// 4x4 register-blocked tile GEMM: acc[i][j] += sum_k src[r0+i][k] * W[k][c0+j]
// ---------------------------------------------------------------------------
__device__ __forceinline__ void tile_mm(const float* src, int S,
                                        const float* __restrict__ W,
                                        int K, int r0, int c0, float acc[4][4]) {
    for (int k = 0; k < K; k += 4) {
        float4 a0 = *(const float4*)(src + (r0 + 0) * S + k);
        float4 a1 = *(const float4*)(src + (r0 + 1) * S + k);
        float4 a2 = *(const float4*)(src + (r0 + 2) * S + k);
        float4 a3 = *(const float4*)(src + (r0 + 3) * S + k);
        float4 w0 = *(const float4*)(W + (k + 0) * HD + c0);
        float4 w1 = *(const float4*)(W + (k + 1) * HD + c0);
        float4 w2 = *(const float4*)(W + (k + 2) * HD + c0);
        float4 w3 = *(const float4*)(W + (k + 3) * HD + c0);
#define ROW(i, av)                                                  \
        acc[i][0] += av.x * w0.x + av.y * w1.x + av.z * w2.x + av.w * w3.x; \
        acc[i][1] += av.x * w0.y + av.y * w1.y + av.z * w2.y + av.w * w3.y; \
        acc[i][2] += av.x * w0.z + av.y * w1.z + av.z * w2.z + av.w * w3.z; \
        acc[i][3] += av.x * w0.w + av.y * w1.w + av.z * w2.w + av.w * w3.w;
        ROW(0, a0) ROW(1, a1) ROW(2, a2) ROW(3, a3)
#undef ROW
    }
}

// ---------------------------------------------------------------------------
// Fused per-node-tile MLP with in-block CSR aggregation. 32 nodes/block.
// ---------------------------------------------------------------------------
extern "C" __global__ void __launch_bounds__(256)
linkx_mlp(const float* __restrict__ x,
          const int* __restrict__ offsets, const int* __restrict__ bucket,
          const float* __restrict__ emb,
          const float* __restrict__ wx1, const float* __restrict__ bx1,
          const float* __restrict__ wx2, const float* __restrict__ bx2,
          const float* __restrict__ wa1, const float* __restrict__ ba1,
          const float* __restrict__ wa2, const float* __restrict__ ba2,
          const float* __restrict__ ww1, const float* __restrict__ bw1,
          const float* __restrict__ wcm, const float* __restrict__ bcv,
          float* __restrict__ out) {
    __shared__ float bufx[32 * 256];
    __shared__ float buft[32 * 128];
    const int t = threadIdx.x;
    const int node0 = blockIdx.x * 32;
    const int r0 = (t >> 5) * 4;
    const int c0 = (t & 31) * 4;
    float* sA = bufx;              // 32x128 slot A (hx)
    float* sB = bufx + 32 * HD;    // 32x128 slot B (ha)
    float acc[4][4];

    // step1: load x tile -> bufx [32][256]
    for (int idx = t; idx < 2048; idx += 256) {
        int r = idx >> 6;
        int c = (idx & 63) * 4;
        *(float4*)(bufx + r * IND + c) =
            *(const float4*)(x + (size_t)(node0 + r) * IND + c);
    }
    __syncthreads();

    // step2: t1 = relu(x @ wx1 + bx1) -> buft
#pragma unroll
    for (int i = 0; i < 4; i++)
#pragma unroll
        for (int j = 0; j < 4; j++) acc[i][j] = 0.f;
    tile_mm(bufx, IND, wx1, IND, r0, c0, acc);
    {
        float4 b = *(const float4*)(bx1 + c0);
#pragma unroll
        for (int i = 0; i < 4; i++) {
            float4 v;
            v.x = fmaxf(acc[i][0] + b.x, 0.f);
            v.y = fmaxf(acc[i][1] + b.y, 0.f);
            v.z = fmaxf(acc[i][2] + b.z, 0.f);
            v.w = fmaxf(acc[i][3] + b.w, 0.f);
            *(float4*)(buft + (r0 + i) * HD + c0) = v;
        }
    }
    __syncthreads();

    // step3: hx = t1 @ wx2 + bx2 (no relu) -> slot A
#pragma unroll
    for (int i = 0; i < 4; i++)
#pragma unroll
        for (int j = 0; j < 4; j++) acc[i][j] = 0.f;
    tile_mm(buft, HD, wx2, HD, r0, c0, acc);
    {
        float4 b = *(const float4*)(bx2 + c0);
#pragma unroll
        for (int i = 0; i < 4; i++) {
            float4 v;
            v.x = acc[i][0] + b.x;
            v.y = acc[i][1] + b.y;
            v.z = acc[i][2] + b.z;
            v.w = acc[i][3] + b.w;
            *(float4*)(sA + (r0 + i) * HD + c0) = v;
        }
    }
    __syncthreads();

    // step4: CSR gather-mean: ha_raw -> slot B.
    // Two 128-thread groups; group handles node r = half, half+2, ...
    // Column col of each gathered emb row; unroll-4 for MLP.
    {
        int col = t & 127;
        int half = t >> 7;
        for (int r = half; r < 32; r += 2) {
            int node = node0 + r;
            int beg = offsets[node];
            int end = offsets[node + 1];
            float a0 = 0.f, a1 = 0.f, a2 = 0.f, a3 = 0.f;
            int i = beg;
            for (; i + 4 <= end; i += 4) {
                int s0 = bucket[i + 0];
                int s1 = bucket[i + 1];
                int s2 = bucket[i + 2];
                int s3 = bucket[i + 3];
                a0 += emb[(size_t)s0 * HD + col];
                a1 += emb[(size_t)s1 * HD + col];
                a2 += emb[(size_t)s2 * HD + col];
                a3 += emb[(size_t)s3 * HD + col];
            }
            for (; i < end; i++) a0 += emb[(size_t)bucket[i] * HD + col];
            float s = (a0 + a1) + (a2 + a3);
            float inv = 1.0f / fmaxf((float)(end - beg), 1.0f);
            sB[r * HD + col] = s * inv;
        }
    }
    __syncthreads();

    // step5: t2 = relu(ha_raw @ wa1 + ba1) -> buft
#pragma unroll
    for (int i = 0; i < 4; i++)
#pragma unroll
        for (int j = 0; j < 4; j++) acc[i][j] = 0.f;
    tile_mm(sB, HD, wa1, HD, r0, c0, acc);
    {
        float4 b = *(const float4*)(ba1 + c0);
#pragma unroll
        for (int i = 0; i < 4; i++) {
            float4 v;
            v.x = fmaxf(acc[i][0] + b.x, 0.f);
            v.y = fmaxf(acc[i][1] + b.y, 0.f);
            v.z = fmaxf(acc[i][2] + b.z, 0.f);
            v.w = fmaxf(acc[i][3] + b.w, 0.f);
            *(float4*)(buft + (r0 + i) * HD + c0) = v;
        }
    }
    __syncthreads();

    // step6: ha = t2 @ wa2 + ba2 (no relu) -> slot B
#pragma unroll
    for (int i = 0; i < 4; i++)
#pragma unroll
        for (int j = 0; j < 4; j++) acc[i][j] = 0.f;
    tile_mm(buft, HD, wa2, HD, r0, c0, acc);
    {
        float4 b = *(const float4*)(ba2 + c0);
#pragma unroll
        for (int i = 0; i < 4; i++) {
            float4 v;
            v.x = acc[i][0] + b.x;
            v.y = acc[i][1] + b.y;
            v.z = acc[i][2] + b.z;
            v.w = acc[i][3] + b.w;
            *(float4*)(sB + (r0 + i) * HD + c0) = v;
        }
    }
    __syncthreads();

    // step7: h = relu(hx @ ww1[0:128] + ha @ ww1[128:256] + bw1) -> buft
#pragma unroll
    for (int i = 0; i < 4; i++)
#pragma unroll
        for (int j = 0; j < 4; j++) acc[i][j] = 0.f;
    tile_mm(sA, HD, ww1, HD, r0, c0, acc);
    tile_mm(sB, HD, ww1 + HD * HD, HD, r0, c0, acc);
    {
        float4 b = *(const float4*)(bw1 + c0);
#pragma unroll
        for (int i = 0; i < 4; i++) {
            float4 v;
            v.x = fmaxf(acc[i][0] + b.x, 0.f);
            v.y = fmaxf(acc[i][1] + b.y, 0.f);
            v.z = fmaxf(acc[i][2] + b.z, 0.f);
            v.w = fmaxf(acc[i][3] + b.w, 0.f);
            *(float4*)(buft + (r0 + i) * HD + c0) = v;
        }
    }
    __syncthreads();

    // step8: h2 = relu(h + hx + ha) in-place in buft
#pragma unroll
    for (int i = 0; i < 4; i++) {
        float4 h = *(const float4*)(buft + (r0 + i) * HD + c0);
        float4 a = *(const float4*)(sA + (r0 + i) * HD + c0);
        float4 b = *(const float4*)(sB + (r0 + i) * HD + c0);
        h.x = fmaxf(h.x + a.x + b.x, 0.f);
        h.y = fmaxf(h.y + a.y + b.y, 0.f);
        h.z = fmaxf(h.z + a.z + b.z, 0.f);
        h.w = fmaxf(h.w + a.w + b.w, 0.f);
        *(float4*)(buft + (r0 + i) * HD + c0) = h;
    }
    __syncthreads();

    // step9: logits = h2 @ wc + bc -> global
    for (int idx = t; idx < 32 * NCLS; idx += 256) {
        int r = idx / NCLS;
        int c = idx - r * NCLS;
        float s = bcv[c];
        const float* hrow = buft + r * HD;
#pragma unroll 4
        for (int k = 0; k < HD; k++) s += hrow[k] * wcm[k * NCLS + c];
        out[(size_t)(node0 + r) * NCLS + c] = s;
    }
}

extern "C" void kernel_launch(void* const* d_in, const int* in_sizes, int n_in,
                              void* d_out, int out_size, void* d_ws, size_t ws_size,
                              hipStream_t stream) {
    const float* x   = (const float*)d_in[0];
    const int*   ei  = (const int*)d_in[1];
    const float* emb = (const float*)d_in[2];
    const float* wx1 = (const float*)d_in[3];
    const float* bx1 = (const float*)d_in[4];
    const float* wx2 = (const float*)d_in[5];
    const float* bx2 = (const float*)d_in[6];
    const float* wa1 = (const float*)d_in[7];
    const float* ba1 = (const float*)d_in[8];
    const float* wa2 = (const float*)d_in[9];
    const float* ba2 = (const float*)d_in[10];
    const float* ww1 = (const float*)d_in[11];
    const float* bw1 = (const float*)d_in[12];
    const float* wc  = (const float*)d_in[13];
    const float* bc  = (const float*)d_in[14];
    float* out = (float*)d_out;

    int* ws = (int*)d_ws;
    int* counts  = ws;                 // [Nn]
    int* pos     = ws + Nn;            // [Nn]
    int* offsets = ws + 2 * Nn;        // [Nn+1]
    int* bsum    = ws + 3 * Nn + 16;   // [NBLK]
    int* bucket  = ws + 3 * Nn + 512;  // [Ee]

    // zero counts + pos (contiguous)
    hipMemsetAsync(ws, 0, (size_t)(2 * Nn) * sizeof(int), stream);

    k_hist<<<Ee / 256, 256, 0, stream>>>(ei, counts);
    k_scan1<<<NBLK, 256, 0, stream>>>(counts, bsum);
    k_scan2<<<1, 512, 0, stream>>>(bsum);
    k_scan3<<<NBLK, 256, 0, stream>>>(counts, bsum, offsets);
    k_scatter<<<Ee / 256, 256, 0, stream>>>(ei, offsets, pos, bucket);

    linkx_mlp<<<Nn / 32, 256, 0, stream>>>(x, offsets, bucket, emb,
                                           wx1, bx1, wx2, bx2,
                                           wa1, ba1, wa2, ba2,
                                           ww1, bw1, wc, bc, out);
}

// Round 3
// 748.475 us; speedup vs baseline: 4.6141x; 1.3928x over previous
//
#include <hip/hip_runtime.h>

#define Nn 100000
#define Ee 1600000
#define IND 256
#define HD 128
#define NCLS 40
#define NBLK 391   // ceil(Nn/256)

typedef _Float16 f16;
typedef f16 f16x8 __attribute__((ext_vector_type(8)));
typedef f16 f16x4 __attribute__((ext_vector_type(4)));
typedef float f32x4 __attribute__((ext_vector_type(4)));

// ---------------------------------------------------------------------------
// CSR build: histogram -> exclusive scan -> bucket scatter.
// ---------------------------------------------------------------------------
extern "C" __global__ void __launch_bounds__(256)
k_hist(const int* __restrict__ ei, int* __restrict__ counts) {
    int e = blockIdx.x * 256 + threadIdx.x;
    if (e < Ee) atomicAdd(&counts[ei[Ee + e]], 1);
}

extern "C" __global__ void __launch_bounds__(256)
k_scan1(const int* __restrict__ counts, int* __restrict__ bsum) {
    __shared__ int s[256];
    int t = threadIdx.x;
    int i = blockIdx.x * 256 + t;
    s[t] = (i < Nn) ? counts[i] : 0;
    __syncthreads();
    for (int d = 128; d > 0; d >>= 1) {
        if (t < d) s[t] += s[t + d];
        __syncthreads();
    }
    if (t == 0) bsum[blockIdx.x] = s[0];
}

extern "C" __global__ void __launch_bounds__(512)
k_scan2(int* __restrict__ bsum) {
    __shared__ int s[512];
    int t = threadIdx.x;
    int v = (t < NBLK) ? bsum[t] : 0;
    s[t] = v;
    __syncthreads();
    for (int d = 1; d < 512; d <<= 1) {
        int x = (t >= d) ? s[t - d] : 0;
        __syncthreads();
        s[t] += x;
        __syncthreads();
    }
    if (t < NBLK) bsum[t] = s[t] - v;
}

extern "C" __global__ void __launch_bounds__(256)
k_scan3(const int* __restrict__ counts, const int* __restrict__ bsum,
        int* __restrict__ offsets) {
    __shared__ int s[256];
    int t = threadIdx.x;
    int i = blockIdx.x * 256 + t;
    int v = (i < Nn) ? counts[i] : 0;
    s[t] = v;
    __syncthreads();
    for (int d = 1; d < 256; d <<= 1) {
        int x = (t >= d) ? s[t - d] : 0;
        __syncthreads();
        s[t] += x;
        __syncthreads();
    }
    if (i < Nn) offsets[i] = bsum[blockIdx.x] + s[t] - v;
    if (i == 0) offsets[Nn] = Ee;
}

extern "C" __global__ void __launch_bounds__(256)
k_scatter(const int* __restrict__ ei, const int* __restrict__ offsets,
          int* __restrict__ pos, int* __restrict__ bucket) {
    int e = blockIdx.x * 256 + threadIdx.x;
    if (e >= Ee) return;
    int dst = ei[Ee + e];
    int p = offsets[dst] + atomicAdd(&pos[dst], 1);
    bucket[p] = ei[e];
}

// ---------------------------------------------------------------------------
// Pack fp32 weight W[K][128] into f16 MFMA-B-fragment layout:
//   P[((ft*KT + kt)*64 + L)*8 + j] = W[kt*32 + (L>>4)*8 + j][ft*16 + (L&15)]
// so a wave's B-frag is one contiguous 16B load per lane.
// ---------------------------------------------------------------------------
extern "C" __global__ void __launch_bounds__(256)
k_pack(const float* __restrict__ W, f16* __restrict__ P, int K, int total) {
    int idx = blockIdx.x * 256 + threadIdx.x;
    if (idx >= total) return;
    int KT = K >> 5;
    int j = idx & 7;
    int L = (idx >> 3) & 63;
    int kt = (idx >> 9) % KT;
    int ft = idx / (512 * KT);
    int k = kt * 32 + (L >> 4) * 8 + j;
    int n = ft * 16 + (L & 15);
    P[idx] = (f16)W[k * HD + n];
}

// ---------------------------------------------------------------------------
// Fused MLP, MFMA f16 edition. 32 nodes/block, 256 threads (4 waves).
// Wave w: mt = w>>1 (node half), fh = w&1 (feature half of 64).
// A-frags from LDS packed buffers (contiguous ds_read_b128);
// B-frags from pre-packed global (contiguous coalesced dwordx4, L2-hot).
// LDS arena 40KB -> 4 blocks/CU.
// ---------------------------------------------------------------------------
extern "C" __global__ void __launch_bounds__(256, 4)
linkx_mlp(const float* __restrict__ x,
          const int* __restrict__ offsets, const int* __restrict__ bucket,
          const float* __restrict__ emb,
          const f16* __restrict__ wx1p, const float* __restrict__ bx1,
          const f16* __restrict__ wx2p, const float* __restrict__ bx2,
          const f16* __restrict__ wa1p, const float* __restrict__ ba1,
          const f16* __restrict__ wa2p, const float* __restrict__ ba2,
          const f16* __restrict__ ww1p, const float* __restrict__ bw1,
          const float* __restrict__ wcm, const float* __restrict__ bcv,
          float* __restrict__ out) {
    __shared__ __align__(16) char arena[40960];
    f16* xp     = (f16*)(arena);           // [0,16384)  x packed, KT=8
    f16* t1p    = (f16*)(arena + 16384);   // [16384,24576) t1 packed KT=4
    f16* hxp    = (f16*)(arena);           // [0,8192)   hx packed (over dead xp)
    f16* hxrm   = (f16*)(arena + 8192);    // [8192,16384) hx row-major 32x128
    f16* harawp = (f16*)(arena + 24576);   // [24576,32768) ha_raw packed
    f16* t2p    = (f16*)(arena + 32768);   // [32768,40960) t2 packed
    f16* hap    = (f16*)(arena + 24576);   // ha packed (over dead harawp)
    f16* harm   = (f16*)(arena + 16384);   // ha row-major (over dead t1p)
    f16* h2rm   = (f16*)(arena + 32768);   // h2 row-major (over dead t2p)

    const int t = threadIdx.x;
    const int node0 = blockIdx.x * 32;
    const int lane = t & 63;
    const int wid = t >> 6;
    const int mt = wid >> 1;   // node 16-tile
    const int fh = wid & 1;    // feature half (4 f-tiles of 16)

    f32x4 acc[4];

#define ZERO_ACC                                               \
    _Pragma("unroll") for (int q = 0; q < 4; q++)              \
    _Pragma("unroll") for (int r = 0; r < 4; r++) acc[q][r] = 0.f;

    // GEMM over K=128: A packed (KT=4) in LDS, B packed global (KT=4)
#define GEMM_K128(APACK, BP)                                                  \
    _Pragma("unroll")                                                         \
    for (int kt = 0; kt < 4; kt++) {                                          \
        f16x8 a = *(const f16x8*)((APACK) + ((mt*4 + kt)*64 + lane)*8);       \
        _Pragma("unroll")                                                     \
        for (int q = 0; q < 4; q++) {                                         \
            f16x8 b = *(const f16x8*)((BP) + (((fh*4+q)*4 + kt)*64 + lane)*8);\
            acc[q] = __builtin_amdgcn_mfma_f32_16x16x32_f16(a, b, acc[q], 0, 0, 0); \
        }                                                                     \
    }

    // Epilogue: acc + bias (+relu) -> packed-A dst (KT=4) and optional row-major
#define EPILOGUE(BIAS, DORELU, PDST, RMDST, DORM)                             \
    _Pragma("unroll")                                                         \
    for (int q = 0; q < 4; q++) {                                             \
        int f = (fh*4 + q)*16 + (lane & 15);                                  \
        float bv = (BIAS)[f];                                                 \
        int kt2 = f >> 5, q2 = (f >> 3) & 3, j2 = f & 7;                      \
        _Pragma("unroll")                                                     \
        for (int r = 0; r < 4; r++) {                                         \
            int n = (lane >> 4)*4 + r;                                        \
            float v = acc[q][r] + bv;                                         \
            if (DORELU) v = fmaxf(v, 0.f);                                    \
            f16 hv = (f16)v;                                                  \
            (PDST)[((mt*4 + kt2)*64 + n + 16*q2)*8 + j2] = hv;                \
            if (DORM) (RMDST)[(mt*16 + n)*HD + f] = hv;                       \
        }                                                                     \
    }

    // step1: x tile -> xp (f16, A-packed, KT=8)
    for (int idx = t; idx < 2048; idx += 256) {
        int m = idx >> 6;
        int k = (idx & 63) * 4;
        float4 v = *(const float4*)(x + (size_t)(node0 + m) * IND + k);
        int mt2 = m >> 4, kt2 = k >> 5, q2 = (k >> 3) & 3, j2 = k & 7;
        f16x4 h;
        h[0] = (f16)v.x; h[1] = (f16)v.y; h[2] = (f16)v.z; h[3] = (f16)v.w;
        *(f16x4*)(xp + ((mt2*8 + kt2)*64 + (m & 15) + 16*q2)*8 + j2) = h;
    }
    __syncthreads();

    // step2: t1 = relu(x @ wx1 + bx1), K=256 (KT=8)
    ZERO_ACC
#pragma unroll
    for (int kt = 0; kt < 8; kt++) {
        f16x8 a = *(const f16x8*)(xp + ((mt*8 + kt)*64 + lane)*8);
#pragma unroll
        for (int q = 0; q < 4; q++) {
            f16x8 b = *(const f16x8*)(wx1p + (((fh*4+q)*8 + kt)*64 + lane)*8);
            acc[q] = __builtin_amdgcn_mfma_f32_16x16x32_f16(a, b, acc[q], 0, 0, 0);
        }
    }
    __syncthreads();   // all xp reads done before epilogue overwrites region? No:
                       // epilogue writes t1p (disjoint). Sync here guards step3's
                       // write of hxp over xp instead.
    EPILOGUE(bx1, 1, t1p, (f16*)0, 0)
    __syncthreads();

    // step3: hx = t1 @ wx2 + bx2 -> hxp (packed) + hxrm (row-major)
    ZERO_ACC
    GEMM_K128(t1p, wx2p)
    EPILOGUE(bx2, 0, hxp, hxrm, 1)

    // step4: CSR gather-mean -> harawp (packed f16). Disjoint LDS region, no
    // sync needed against step3.
    {
        int col = t & 127;
        int half = t >> 7;
        int qpart = 16 * ((col >> 3) & 3);
        int ktc = col >> 5;
        int jc = col & 7;
        for (int r = half; r < 32; r += 2) {
            int node = node0 + r;
            int beg = offsets[node];
            int end = offsets[node + 1];
            float a0 = 0.f, a1 = 0.f, a2 = 0.f, a3 = 0.f;
            int i = beg;
            for (; i + 4 <= end; i += 4) {
                int s0 = bucket[i + 0];
                int s1 = bucket[i + 1];
                int s2 = bucket[i + 2];
                int s3 = bucket[i + 3];
                a0 += emb[(size_t)s0 * HD + col];
                a1 += emb[(size_t)s1 * HD + col];
                a2 += emb[(size_t)s2 * HD + col];
                a3 += emb[(size_t)s3 * HD + col];
            }
            for (; i < end; i++) a0 += emb[(size_t)bucket[i] * HD + col];
            float s = (a0 + a1) + (a2 + a3);
            float inv = 1.0f / fmaxf((float)(end - beg), 1.0f);
            harawp[(((r >> 4)*4 + ktc)*64 + (r & 15) + qpart)*8 + jc] =
                (f16)(s * inv);
        }
    }
    __syncthreads();

    // step5: t2 = relu(ha_raw @ wa1 + ba1) -> t2p
    ZERO_ACC
    GEMM_K128(harawp, wa1p)
    EPILOGUE(ba1, 1, t2p, (f16*)0, 0)
    __syncthreads();

    // step6: ha = t2 @ wa2 + ba2 -> hap (over harawp) + harm (over t1p)
    ZERO_ACC
    GEMM_K128(t2p, wa2p)
    EPILOGUE(ba2, 0, hap, harm, 1)
    __syncthreads();

    // step7+8: h = relu([hx|ha] @ ww1 + bw1); h2 = relu(h+hx+ha) -> h2rm
    ZERO_ACC
#pragma unroll
    for (int kt = 0; kt < 8; kt++) {
        const f16* ap = (kt < 4) ? (hxp + ((mt*4 + kt)*64 + lane)*8)
                                 : (hap + ((mt*4 + (kt-4))*64 + lane)*8);
        f16x8 a = *(const f16x8*)ap;
#pragma unroll
        for (int q = 0; q < 4; q++) {
            f16x8 b = *(const f16x8*)(ww1p + (((fh*4+q)*8 + kt)*64 + lane)*8);
            acc[q] = __builtin_amdgcn_mfma_f32_16x16x32_f16(a, b, acc[q], 0, 0, 0);
        }
    }
#pragma unroll
    for (int q = 0; q < 4; q++) {
        int f = (fh*4 + q)*16 + (lane & 15);
        float bv = bw1[f];
#pragma unroll
        for (int r = 0; r < 4; r++) {
            int n = mt*16 + (lane >> 4)*4 + r;
            float h = fmaxf(acc[q][r] + bv, 0.f);
            float v = h + (float)hxrm[n*HD + f] + (float)harm[n*HD + f];
            h2rm[n*HD + f] = (f16)fmaxf(v, 0.f);
        }
    }
    __syncthreads();

    // step9: logits = h2 @ wc + bc
    for (int idx = t; idx < 32 * NCLS; idx += 256) {
        int r = idx / NCLS;
        int c = idx - r * NCLS;
        float s = bcv[c];
        const f16* hrow = h2rm + r * HD;
#pragma unroll 4
        for (int k = 0; k < HD; k++) s += (float)hrow[k] * wcm[k * NCLS + c];
        out[(size_t)(node0 + r) * NCLS + c] = s;
    }
}

extern "C" void kernel_launch(void* const* d_in, const int* in_sizes, int n_in,
                              void* d_out, int out_size, void* d_ws, size_t ws_size,
                              hipStream_t stream) {
    const float* x   = (const float*)d_in[0];
    const int*   ei  = (const int*)d_in[1];
    const float* emb = (const float*)d_in[2];
    const float* wx1 = (const float*)d_in[3];
    const float* bx1 = (const float*)d_in[4];
    const float* wx2 = (const float*)d_in[5];
    const float* bx2 = (const float*)d_in[6];
    const float* wa1 = (const float*)d_in[7];
    const float* ba1 = (const float*)d_in[8];
    const float* wa2 = (const float*)d_in[9];
    const float* ba2 = (const float*)d_in[10];
    const float* ww1 = (const float*)d_in[11];
    const float* bw1 = (const float*)d_in[12];
    const float* wc  = (const float*)d_in[13];
    const float* bc  = (const float*)d_in[14];
    float* out = (float*)d_out;

    int* ws = (int*)d_ws;
    int* counts  = ws;                 // [Nn]
    int* pos     = ws + Nn;            // [Nn]
    int* offsets = ws + 2 * Nn;        // [Nn+1]
    int* bsum    = ws + 3 * Nn + 16;   // [NBLK]
    int* bucket  = ws + 3 * Nn + 512;  // [Ee]
    f16* wp      = (f16*)(ws + 3 * Nn + 512 + Ee);  // 16B-aligned
    f16* wx1p = wp;            // 256*128
    f16* wx2p = wp + 32768;    // 128*128
    f16* wa1p = wp + 49152;
    f16* wa2p = wp + 65536;
    f16* ww1p = wp + 81920;    // 256*128

    hipMemsetAsync(ws, 0, (size_t)(2 * Nn) * sizeof(int), stream);

    k_hist<<<Ee / 256, 256, 0, stream>>>(ei, counts);
    k_scan1<<<NBLK, 256, 0, stream>>>(counts, bsum);
    k_scan2<<<1, 512, 0, stream>>>(bsum);
    k_scan3<<<NBLK, 256, 0, stream>>>(counts, bsum, offsets);
    k_scatter<<<Ee / 256, 256, 0, stream>>>(ei, offsets, pos, bucket);

    k_pack<<<128, 256, 0, stream>>>(wx1, wx1p, 256, 32768);
    k_pack<<<64, 256, 0, stream>>>(wx2, wx2p, 128, 16384);
    k_pack<<<64, 256, 0, stream>>>(wa1, wa1p, 128, 16384);
    k_pack<<<64, 256, 0, stream>>>(wa2, wa2p, 128, 16384);
    k_pack<<<128, 256, 0, stream>>>(ww1, ww1p, 256, 32768);

    linkx_mlp<<<Nn / 32, 256, 0, stream>>>(x, offsets, bucket, emb,
                                           wx1p, bx1, wx2p, bx2,
                                           wa1p, ba1, wa2p, ba2,
                                           ww1p, bw1, wc, bc, out);
}

// Round 4
// 562.940 us; speedup vs baseline: 6.1348x; 1.3296x over previous
//
#include <hip/hip_runtime.h>

#define Nn 100000
#define Ee 1600000
#define IND 256
#define HD 128
#define NCLS 40
#define NBLK 391   // ceil(Nn/256)

typedef _Float16 f16;
typedef f16 f16x8 __attribute__((ext_vector_type(8)));
typedef f16 f16x4 __attribute__((ext_vector_type(4)));
typedef float f32x4 __attribute__((ext_vector_type(4)));

// ---------------------------------------------------------------------------
// CSR build: histogram -> exclusive scan -> bucket scatter.
// ---------------------------------------------------------------------------
extern "C" __global__ void __launch_bounds__(256)
k_hist(const int* __restrict__ ei, int* __restrict__ counts) {
    int e = blockIdx.x * 256 + threadIdx.x;
    if (e < Ee) atomicAdd(&counts[ei[Ee + e]], 1);
}

extern "C" __global__ void __launch_bounds__(256)
k_scan1(const int* __restrict__ counts, int* __restrict__ bsum) {
    __shared__ int s[256];
    int t = threadIdx.x;
    int i = blockIdx.x * 256 + t;
    s[t] = (i < Nn) ? counts[i] : 0;
    __syncthreads();
    for (int d = 128; d > 0; d >>= 1) {
        if (t < d) s[t] += s[t + d];
        __syncthreads();
    }
    if (t == 0) bsum[blockIdx.x] = s[0];
}

extern "C" __global__ void __launch_bounds__(512)
k_scan2(int* __restrict__ bsum) {
    __shared__ int s[512];
    int t = threadIdx.x;
    int v = (t < NBLK) ? bsum[t] : 0;
    s[t] = v;
    __syncthreads();
    for (int d = 1; d < 512; d <<= 1) {
        int x = (t >= d) ? s[t - d] : 0;
        __syncthreads();
        s[t] += x;
        __syncthreads();
    }
    if (t < NBLK) bsum[t] = s[t] - v;
}

extern "C" __global__ void __launch_bounds__(256)
k_scan3(const int* __restrict__ counts, const int* __restrict__ bsum,
        int* __restrict__ offsets) {
    __shared__ int s[256];
    int t = threadIdx.x;
    int i = blockIdx.x * 256 + t;
    int v = (i < Nn) ? counts[i] : 0;
    s[t] = v;
    __syncthreads();
    for (int d = 1; d < 256; d <<= 1) {
        int x = (t >= d) ? s[t - d] : 0;
        __syncthreads();
        s[t] += x;
        __syncthreads();
    }
    if (i < Nn) offsets[i] = bsum[blockIdx.x] + s[t] - v;
    if (i == 0) offsets[Nn] = Ee;
}

extern "C" __global__ void __launch_bounds__(256)
k_scatter(const int* __restrict__ ei, const int* __restrict__ offsets,
          int* __restrict__ pos, int* __restrict__ bucket) {
    int e = blockIdx.x * 256 + threadIdx.x;
    if (e >= Ee) return;
    int dst = ei[Ee + e];
    int p = offsets[dst] + atomicAdd(&pos[dst], 1);
    bucket[p] = ei[e];
}

// ---------------------------------------------------------------------------
// Fused weight pack: all 5 MLP weights + zero-padded wc into f16 B-frag layout
//   P[((ft*KT+kt)*64+L)*8+j] = W[kt*32+(L>>4)*8+j][ft*16+(L&15)]
// Segment boundaries all multiples of 256 -> wave-uniform branches.
// ---------------------------------------------------------------------------
extern "C" __global__ void __launch_bounds__(256)
k_wpack(const float* __restrict__ wx1, const float* __restrict__ wx2,
        const float* __restrict__ wa1, const float* __restrict__ wa2,
        const float* __restrict__ ww1, const float* __restrict__ wc,
        f16* __restrict__ wp) {
    int idx = blockIdx.x * 256 + threadIdx.x;
    const float* W;
    int K, base;
    if (idx < 32768)       { W = wx1; K = 256; base = 0; }
    else if (idx < 49152)  { W = wx2; K = 128; base = 32768; }
    else if (idx < 65536)  { W = wa1; K = 128; base = 49152; }
    else if (idx < 81920)  { W = wa2; K = 128; base = 65536; }
    else if (idx < 114688) { W = ww1; K = 256; base = 81920; }
    else {
        // wc: [HD][NCLS] row-major, padded to 48 cols (3 ftiles), KT=4
        int local = idx - 114688;   // < 6144
        int j = local & 7;
        int L = (local >> 3) & 63;
        int kt = (local >> 9) & 3;
        int ft = local / 2048;
        int k = kt * 32 + (L >> 4) * 8 + j;
        int n = ft * 16 + (L & 15);
        wp[idx] = (n < NCLS) ? (f16)wc[k * NCLS + n] : (f16)0.f;
        return;
    }
    int local = idx - base;
    int KT = K >> 5;
    int j = local & 7;
    int L = (local >> 3) & 63;
    int kt = (local >> 9) % KT;
    int ft = local / (512 * KT);
    int k = kt * 32 + (L >> 4) * 8 + j;
    int n = ft * 16 + (L & 15);
    wp[idx] = (f16)W[k * HD + n];
}

// ---------------------------------------------------------------------------
// Gather-mean: one wave per node. lanes 0-31 / 32-63 process alternating
// edges; each lane covers 4 cols (float4). Result written f16 in MFMA
// A-fragment packed layout: harawp[((nt*4+kt)*64 + (m&15)+16*q2)*8+j2].
// ---------------------------------------------------------------------------
extern "C" __global__ void __launch_bounds__(256)
k_gather(const int* __restrict__ offsets, const int* __restrict__ bucket,
         const float* __restrict__ emb, f16* __restrict__ harawp) {
    int t = threadIdx.x;
    int lane = t & 63;
    int node = blockIdx.x * 4 + (t >> 6);
    int half = lane >> 5;
    int cl = (lane & 31) * 4;

    int beg = offsets[node];
    int end = offsets[node + 1];
    float sx = 0.f, sy = 0.f, sz = 0.f, sw = 0.f;
    int i = beg + half;
    for (; i + 2 < end; i += 4) {
        int s0 = bucket[i];
        int s1 = bucket[i + 2];
        float4 a = *(const float4*)(emb + (size_t)s0 * HD + cl);
        float4 b = *(const float4*)(emb + (size_t)s1 * HD + cl);
        sx += a.x + b.x; sy += a.y + b.y; sz += a.z + b.z; sw += a.w + b.w;
    }
    for (; i < end; i += 2) {
        int s0 = bucket[i];
        float4 a = *(const float4*)(emb + (size_t)s0 * HD + cl);
        sx += a.x; sy += a.y; sz += a.z; sw += a.w;
    }
    // cross-half reduce (lane += lane+32)
    sx += __shfl_down(sx, 32);
    sy += __shfl_down(sy, 32);
    sz += __shfl_down(sz, 32);
    sw += __shfl_down(sw, 32);
    if (half == 0) {
        float inv = 1.0f / fmaxf((float)(end - beg), 1.0f);
        f16x4 h;
        h[0] = (f16)(sx * inv); h[1] = (f16)(sy * inv);
        h[2] = (f16)(sz * inv); h[3] = (f16)(sw * inv);
        int nt = node >> 4, m = node & 15;
        int kt = cl >> 5, q2 = (cl >> 3) & 3, j2 = cl & 7;
        *(f16x4*)(harawp + (((nt * 4 + kt) * 64 + m + 16 * q2) * 8 + j2)) = h;
    }
}

// ---------------------------------------------------------------------------
// Fused MLP, all-MFMA. 32 nodes/block, 4 waves: mt=wid>>1 (node 16-tile),
// fh=wid&1 (feature half). A-frags: x + haraw direct from global (coalesced,
// f16-packed for haraw, fp32+cvt for x); B-frags: packed weights from global
// (L2-hot). LDS 24KB (shared t1p/t2p/h2p + hxp + hap) -> 5+ blocks/CU.
// Residual hx+ha kept in registers (same C-tile mapping across steps).
// ---------------------------------------------------------------------------
extern "C" __global__ void __launch_bounds__(256, 5)
linkx_mlp(const float* __restrict__ x, const f16* __restrict__ harawp,
          const f16* __restrict__ wx1p, const float* __restrict__ bx1,
          const f16* __restrict__ wx2p, const float* __restrict__ bx2,
          const f16* __restrict__ wa1p, const float* __restrict__ ba1,
          const f16* __restrict__ wa2p, const float* __restrict__ ba2,
          const f16* __restrict__ ww1p, const float* __restrict__ bw1,
          const f16* __restrict__ wcp, const float* __restrict__ bc,
          float* __restrict__ out) {
    __shared__ __align__(16) f16 shr[4096];   // t1p / t2p / h2p (8KB shared)
    __shared__ __align__(16) f16 hxp[4096];   // hx packed (8KB)
    __shared__ __align__(16) f16 hap[4096];   // ha packed (8KB)

    const int t = threadIdx.x;
    const int node0 = blockIdx.x * 32;
    const int lane = t & 63;
    const int wid = t >> 6;
    const int mt = wid >> 1;
    const int fh = wid & 1;

    f32x4 acc[4];
    float rreg[4][4];   // hx+ha residual, same C-tile as acc

#define INIT_ACC(BIAS)                                                    \
    _Pragma("unroll")                                                     \
    for (int q = 0; q < 4; q++) {                                         \
        float bv = (BIAS)[(fh * 4 + q) * 16 + (lane & 15)];               \
        acc[q][0] = bv; acc[q][1] = bv; acc[q][2] = bv; acc[q][3] = bv;   \
    }

#define GEMM_K128(APACK, BP)                                                  \
    _Pragma("unroll")                                                         \
    for (int kt = 0; kt < 4; kt++) {                                          \
        f16x8 a = *(const f16x8*)((APACK) + ((mt * 4 + kt) * 64 + lane) * 8); \
        _Pragma("unroll")                                                     \
        for (int q = 0; q < 4; q++) {                                         \
            f16x8 b = *(const f16x8*)((BP) + (((fh*4+q)*4 + kt)*64 + lane)*8);\
            acc[q] = __builtin_amdgcn_mfma_f32_16x16x32_f16(a, b, acc[q], 0, 0, 0); \
        }                                                                     \
    }

    // Epilogue -> packed LDS dst; MODE 0: relu, 1: no relu + rreg=v,
    // 2: no relu + rreg+=v, 3: h=relu(acc); v=relu(h+rreg)
#define EPILOGUE(MODE, PDST)                                                  \
    _Pragma("unroll")                                                         \
    for (int q = 0; q < 4; q++) {                                             \
        int f = (fh * 4 + q) * 16 + (lane & 15);                              \
        int kt2 = f >> 5, q2 = (f >> 3) & 3, j2 = f & 7;                      \
        _Pragma("unroll")                                                     \
        for (int r = 0; r < 4; r++) {                                         \
            int n = (lane >> 4) * 4 + r;                                      \
            float v = acc[q][r];                                              \
            if (MODE == 0) v = fmaxf(v, 0.f);                                 \
            if (MODE == 1) rreg[q][r] = v;                                    \
            if (MODE == 2) rreg[q][r] += v;                                   \
            if (MODE == 3) v = fmaxf(fmaxf(v, 0.f) + rreg[q][r], 0.f);        \
            (PDST)[((mt * 4 + kt2) * 64 + n + 16 * q2) * 8 + j2] = (f16)v;    \
        }                                                                     \
    }

    // step2: t1 = relu(x @ wx1 + bx1), K=256; A from global x (fp32->f16)
    INIT_ACC(bx1)
#pragma unroll
    for (int kt = 0; kt < 8; kt++) {
        const float* xr = x + (size_t)(node0 + mt * 16 + (lane & 15)) * IND
                            + kt * 32 + (lane >> 4) * 8;
        float4 u0 = *(const float4*)(xr);
        float4 u1 = *(const float4*)(xr + 4);
        f16x8 a;
        a[0] = (f16)u0.x; a[1] = (f16)u0.y; a[2] = (f16)u0.z; a[3] = (f16)u0.w;
        a[4] = (f16)u1.x; a[5] = (f16)u1.y; a[6] = (f16)u1.z; a[7] = (f16)u1.w;
#pragma unroll
        for (int q = 0; q < 4; q++) {
            f16x8 b = *(const f16x8*)(wx1p + (((fh*4+q)*8 + kt)*64 + lane)*8);
            acc[q] = __builtin_amdgcn_mfma_f32_16x16x32_f16(a, b, acc[q], 0, 0, 0);
        }
    }
    EPILOGUE(0, shr)          // t1p
    __syncthreads();

    // step3: hx = t1 @ wx2 + bx2 -> hxp, rreg = hx
    INIT_ACC(bx2)
    GEMM_K128(shr, wx2p)
    EPILOGUE(1, hxp)
    __syncthreads();          // t1p reads done -> shr reusable

    // step5: t2 = relu(haraw @ wa1 + ba1); A direct from global packed f16
    INIT_ACC(ba1)
    {
        int ntb = (node0 >> 4) + mt;
#pragma unroll
        for (int kt = 0; kt < 4; kt++) {
            f16x8 a = *(const f16x8*)(harawp + ((ntb * 4 + kt) * 64 + lane) * 8);
#pragma unroll
            for (int q = 0; q < 4; q++) {
                f16x8 b = *(const f16x8*)(wa1p + (((fh*4+q)*4 + kt)*64 + lane)*8);
                acc[q] = __builtin_amdgcn_mfma_f32_16x16x32_f16(a, b, acc[q], 0, 0, 0);
            }
        }
    }
    EPILOGUE(0, shr)          // t2p
    __syncthreads();

    // step6: ha = t2 @ wa2 + ba2 -> hap, rreg += ha
    INIT_ACC(ba2)
    GEMM_K128(shr, wa2p)
    EPILOGUE(2, hap)
    __syncthreads();          // t2p reads done -> shr reusable

    // step7+8: h2 = relu(relu([hx|ha] @ ww1 + bw1) + hx + ha) -> h2p
    INIT_ACC(bw1)
#pragma unroll
    for (int kt = 0; kt < 8; kt++) {
        const f16* ap = (kt < 4) ? (hxp + ((mt * 4 + kt) * 64 + lane) * 8)
                                 : (hap + ((mt * 4 + (kt - 4)) * 64 + lane) * 8);
        f16x8 a = *(const f16x8*)ap;
#pragma unroll
        for (int q = 0; q < 4; q++) {
            f16x8 b = *(const f16x8*)(ww1p + (((fh*4+q)*8 + kt)*64 + lane)*8);
            acc[q] = __builtin_amdgcn_mfma_f32_16x16x32_f16(a, b, acc[q], 0, 0, 0);
        }
    }
    EPILOGUE(3, shr)          // h2p
    __syncthreads();

    // step9: logits = h2 @ wc + bc (MFMA, 3 ftiles: fh0 -> {0,2}, fh1 -> {1})
    {
        int nft = (fh == 0) ? 2 : 1;
#pragma unroll 2
        for (int ii = 0; ii < nft; ii++) {
            int ft = (ii == 0) ? fh : 2;
            int f = ft * 16 + (lane & 15);
            f32x4 c;
            float bv = (f < NCLS) ? bc[f] : 0.f;
            c[0] = bv; c[1] = bv; c[2] = bv; c[3] = bv;
#pragma unroll
            for (int kt = 0; kt < 4; kt++) {
                f16x8 a = *(const f16x8*)(shr + ((mt * 4 + kt) * 64 + lane) * 8);
                f16x8 b = *(const f16x8*)(wcp + ((ft * 4 + kt) * 64 + lane) * 8);
                c = __builtin_amdgcn_mfma_f32_16x16x32_f16(a, b, c, 0, 0, 0);
            }
            if (f < NCLS) {
#pragma unroll
                for (int r = 0; r < 4; r++) {
                    int n = node0 + mt * 16 + (lane >> 4) * 4 + r;
                    out[(size_t)n * NCLS + f] = c[r];
                }
            }
        }
    }
}

extern "C" void kernel_launch(void* const* d_in, const int* in_sizes, int n_in,
                              void* d_out, int out_size, void* d_ws, size_t ws_size,
                              hipStream_t stream) {
    const float* x   = (const float*)d_in[0];
    const int*   ei  = (const int*)d_in[1];
    const float* emb = (const float*)d_in[2];
    const float* wx1 = (const float*)d_in[3];
    const float* bx1 = (const float*)d_in[4];
    const float* wx2 = (const float*)d_in[5];
    const float* bx2 = (const float*)d_in[6];
    const float* wa1 = (const float*)d_in[7];
    const float* ba1 = (const float*)d_in[8];
    const float* wa2 = (const float*)d_in[9];
    const float* ba2 = (const float*)d_in[10];
    const float* ww1 = (const float*)d_in[11];
    const float* bw1 = (const float*)d_in[12];
    const float* wc  = (const float*)d_in[13];
    const float* bc  = (const float*)d_in[14];
    float* out = (float*)d_out;

    int* ws = (int*)d_ws;
    int* counts  = ws;                 // [Nn]
    int* pos     = ws + Nn;            // [Nn]
    int* offsets = ws + 2 * Nn;        // [Nn+1]
    int* bsum    = ws + 3 * Nn + 16;   // [NBLK]
    int* bucket  = ws + 3 * Nn + 512;  // [Ee]
    f16* wp      = (f16*)(ws + 3 * Nn + 512 + Ee);  // 120832 f16 (16B aligned)
    f16* wx1p = wp;                 // 32768
    f16* wx2p = wp + 32768;         // 16384
    f16* wa1p = wp + 49152;         // 16384
    f16* wa2p = wp + 65536;         // 16384
    f16* ww1p = wp + 81920;         // 32768
    f16* wcp  = wp + 114688;        // 6144
    f16* harawp = wp + 131072;      // [Nn*HD] f16, A-packed

    hipMemsetAsync(ws, 0, (size_t)(2 * Nn) * sizeof(int), stream);

    k_hist<<<Ee / 256, 256, 0, stream>>>(ei, counts);
    k_scan1<<<NBLK, 256, 0, stream>>>(counts, bsum);
    k_scan2<<<1, 512, 0, stream>>>(bsum);
    k_scan3<<<NBLK, 256, 0, stream>>>(counts, bsum, offsets);
    k_scatter<<<Ee / 256, 256, 0, stream>>>(ei, offsets, pos, bucket);
    k_wpack<<<472, 256, 0, stream>>>(wx1, wx2, wa1, wa2, ww1, wc, wp);
    k_gather<<<Nn / 4, 256, 0, stream>>>(offsets, bucket, emb, harawp);

    linkx_mlp<<<Nn / 32, 256, 0, stream>>>(x, harawp,
                                           wx1p, bx1, wx2p, bx2,
                                           wa1p, ba1, wa2p, ba2,
                                           ww1p, bw1, wcp, bc, out);
}